// Round 10
// baseline (309.404 us; speedup 1.0000x reference)
//
#include <hip/hip_runtime.h>
#include <math.h>

// Problem geometry (fixed by setup_inputs)
#define NN 2
#define DD 160
#define HH 192
#define WW 160
#define DO 154   // DD-6
#define HO 186   // HH-6
#define WO 154   // WW-6

#define NWO 3    // wo tiles of 64
#define NHO 47   // ho tiles of 4
#define ZCH 8    // z chunks
#define ZOC 20   // ceil(DO/ZCH)
#define NB (NWO * NHO * NN * ZCH)   // 2256 blocks

// LDS-only barrier: s_waitcnt lgkmcnt(0) (vmcnt left outstanding) + s_barrier.
#define LDS_SYNC() do { __builtin_amdgcn_s_waitcnt(0xC07F); __builtin_amdgcn_s_barrier(); } while (0)

typedef __attribute__((ext_vector_type(2))) float f2;   // -> v_pk_*_f32

__device__ __forceinline__ unsigned mono_f2u(float f) {
  unsigned u = __float_as_uint(f);
  return (u & 0x80000000u) ? ~u : (u | 0x80000000u);
}

__device__ __forceinline__ float block_sum(float v, float* sm) {
  int tid = threadIdx.x;
  sm[tid] = v;
  __syncthreads();
#pragma unroll
  for (int off = 128; off > 0; off >>= 1) {
    if (tid < off) sm[tid] += sm[tid + off];
    __syncthreads();
  }
  float r = sm[0];
  __syncthreads();
  return r;
}

__device__ __forceinline__ float block_min(float v, float* sm) {
  int tid = threadIdx.x;
  sm[tid] = v;
  __syncthreads();
#pragma unroll
  for (int off = 128; off > 0; off >>= 1) {
    if (tid < off) sm[tid] = fminf(sm[tid], sm[tid + off]);
    __syncthreads();
  }
  float r = sm[0];
  __syncthreads();
  return r;
}

// acc layout (floats): [0..3] = snv, sn, sv, cnt (zeroed);
// [4] = vmin monotone-uint (init 0xFFFFFFFF); [5] = arrival counter (zeroed).
__global__ __launch_bounds__(256, 4) void ncc_fused(const float* __restrict__ X,
                                                    const float* __restrict__ Y,
                                                    float* __restrict__ acc,
                                                    float* __restrict__ out) {
  // Channel-paired LDS: (sx,sy) and (sxx,syy) as f2, sxy scalar.
  __shared__ __align__(16) f2    R01[10][64];   // 5.12 KB
  __shared__ __align__(16) f2    R23[10][64];   // 5.12 KB
  __shared__ __align__(16) float R4 [10][64];   // 2.56 KB
  __shared__ __align__(16) f2    Mh01[4][64];   // 2 KB
  __shared__ __align__(16) f2    Mh23[4][64];   // 2 KB
  __shared__ __align__(16) float Mh4 [4][64];   // 1 KB
  __shared__ float sm[256];

  const int tid = threadIdx.x;
  const int tx = tid & 63, ty = tid >> 6;
  const int wo0 = blockIdx.x * 64;
  const int ho0 = blockIdx.y * 4;
  const int n   = blockIdx.z >> 3;   // ZCH == 8
  const int ck  = blockIdx.z & 7;
  const int z0  = ck * ZOC;
  const int zout = min(ZOC, DO - z0);
  const int nslice = zout + 6;

  const int wo = wo0 + tx, ho = ho0 + ty;
  const bool act = (wo < WO) && (ho < HO);

  const size_t slice = (size_t)HH * WW;
  const float* Xn = X + (size_t)n * DD * slice;
  const float* Yn = Y + (size_t)n * DD * slice;
  const float inv_nw = 1.0f / 343.0f;
  const float LO = -1.0f - 1e-5f, HI = 1.0f + 1e-5f;

  // Phase-A quad item: 160 items, item p -> row r=p>>4 (0..9), cols cq..cq+3.
  const int pA  = tid;
  const bool hasA = (pA < 160);
  const int rA  = pA >> 4;
  const int cqA = (pA & 15) << 2;
  const int hA  = ho0 + rA;
  const int baseW = wo0 + cqA;                 // multiple of 4, <=152 when valid
  const bool okA  = hasA && (hA < HH) && (baseW < WO);
  const bool tail = okA && (baseW + 9 >= WW);  // last float2 would cross the row
  const float* XrowA = Xn + (size_t)hA * WW + baseW;
  const float* YrowA = Yn + (size_t)hA * WW + baseW;

  float4 lx0 = {0,0,0,0}, lx1 = {0,0,0,0}, ly0 = {0,0,0,0}, ly1 = {0,0,0,0};
  float2 lx2 = {0,0}, ly2 = {0,0};

  auto loadA = [&](int s_in) {
    if (okA) {
      const float* xp = XrowA + (size_t)(z0 + s_in) * slice;
      const float* yp = YrowA + (size_t)(z0 + s_in) * slice;
      lx0 = *(const float4*)xp; lx1 = *(const float4*)(xp + 4);
      ly0 = *(const float4*)yp; ly1 = *(const float4*)(yp + 4);
      if (!tail) { lx2 = *(const float2*)(xp + 8); ly2 = *(const float2*)(yp + 8); }
      else       { lx2 = make_float2(0.f, 0.f);    ly2 = make_float2(0.f, 0.f); }
    }
  };

  auto storeA = [&]() {
    if (okA) {
      float x[10] = {lx0.x,lx0.y,lx0.z,lx0.w,lx1.x,lx1.y,lx1.z,lx1.w,lx2.x,lx2.y};
      float y[10] = {ly0.x,ly0.y,ly0.z,ly0.w,ly1.x,ly1.y,ly1.z,ly1.w,ly2.x,ly2.y};
      f2 s[10], q[10];
#pragma unroll
      for (int i = 0; i < 10; ++i) { s[i] = f2{x[i], y[i]}; q[i] = s[i] * s[i]; }
      {
        f2 a = s[0]+s[1]+s[2]+s[3]+s[4]+s[5]+s[6];
        f2 b = a - s[0] + s[7], c = b - s[1] + s[8], d = c - s[2] + s[9];
        *(float4*)&R01[rA][cqA]     = make_float4(a.x, a.y, b.x, b.y);
        *(float4*)&R01[rA][cqA + 2] = make_float4(c.x, c.y, d.x, d.y);
      }
      {
        f2 a = q[0]+q[1]+q[2]+q[3]+q[4]+q[5]+q[6];
        f2 b = a - q[0] + q[7], c = b - q[1] + q[8], d = c - q[2] + q[9];
        *(float4*)&R23[rA][cqA]     = make_float4(a.x, a.y, b.x, b.y);
        *(float4*)&R23[rA][cqA + 2] = make_float4(c.x, c.y, d.x, d.y);
      }
      {
        float a = x[0]*y[0]+x[1]*y[1]+x[2]*y[2]+x[3]*y[3]+x[4]*y[4]+x[5]*y[5]+x[6]*y[6];
        float b = a - x[0]*y[0] + x[7]*y[7];
        float c = b - x[1]*y[1] + x[8]*y[8];
        float d = c - x[2]*y[2] + x[9]*y[9];
        *(float4*)&R4[rA][cqA] = make_float4(a, b, c, d);
      }
    }
  };

  // Phase H: incremental 7-tap H-sums. Wave 0 -> R01 (f2), wave 1 -> R23 (f2),
  // wave 2 -> R4 (scalar), wave 3 idle.
  auto phaseH = [&]() {
    if (ty == 0) {
      const int w = tx;
      f2 r0=R01[0][w],r1=R01[1][w],r2=R01[2][w],r3=R01[3][w],r4=R01[4][w],
         r5=R01[5][w],r6=R01[6][w],r7=R01[7][w],r8=R01[8][w],r9=R01[9][w];
      f2 m0 = r0+r1+r2+r3+r4+r5+r6;
      f2 m1 = m0 - r0 + r7, m2 = m1 - r1 + r8, m3 = m2 - r2 + r9;
      Mh01[0][w]=m0; Mh01[1][w]=m1; Mh01[2][w]=m2; Mh01[3][w]=m3;
    } else if (ty == 1) {
      const int w = tx;
      f2 r0=R23[0][w],r1=R23[1][w],r2=R23[2][w],r3=R23[3][w],r4=R23[4][w],
         r5=R23[5][w],r6=R23[6][w],r7=R23[7][w],r8=R23[8][w],r9=R23[9][w];
      f2 m0 = r0+r1+r2+r3+r4+r5+r6;
      f2 m1 = m0 - r0 + r7, m2 = m1 - r1 + r8, m3 = m2 - r2 + r9;
      Mh23[0][w]=m0; Mh23[1][w]=m1; Mh23[2][w]=m2; Mh23[3][w]=m3;
    } else if (ty == 2) {
      const int w = tx;
      const float* rp = &R4[0][w];
      float r0=rp[0],r1=rp[64],r2=rp[128],r3=rp[192],r4=rp[256],
            r5=rp[320],r6=rp[384],r7=rp[448],r8=rp[512],r9=rp[576];
      float m0 = r0+r1+r2+r3+r4+r5+r6;
      float m1 = m0 - r0 + r7, m2 = m1 - r1 + r8, m3 = m2 - r2 + r9;
      Mh4[0][w]=m0; Mh4[1][w]=m1; Mh4[2][w]=m2; Mh4[3][w]=m3;
    }
  };

  // z-window via per-chunk prefix sums + 7-deep history ring (compile-time u).
  f2 P01 = {0.f, 0.f}, P23 = {0.f, 0.f};
  float P4 = 0.f;
  f2 H01[7], H23[7];
  float H4[7];
#pragma unroll
  for (int j = 0; j < 7; ++j) { H01[j] = f2{0.f, 0.f}; H23[j] = f2{0.f, 0.f}; H4[j] = 0.f; }
  float p_snv = 0.f, p_sn = 0.f, p_sv = 0.f, p_cnt = 0.f, p_vmin = 3.4e38f;

  loadA(0);
  storeA();
  __syncthreads();

  for (int sb = 0; sb < nslice; sb += 7) {
#pragma unroll
    for (int u = 0; u < 7; ++u) {
      const int s = sb + u;
      if (s < nslice) {                       // block-uniform
        if (s + 1 < nslice) loadA(s + 1);     // global -> regs (stays in flight)
        phaseH();                             // R -> Mh
        LDS_SYNC();
        {                                      // Phase O: prefix + window diff + NCC
          f2 m01 = Mh01[ty][tx], m23 = Mh23[ty][tx];
          float m4 = Mh4[ty][tx];
          P01 += m01; P23 += m23; P4 += m4;
          if (s >= 6 && act) {
            f2 d01 = P01 - H01[u];            // (zs0, zs1)
            f2 d23 = P23 - H23[u];            // (zs2, zs3)
            float zs4 = P4 - H4[u];
            float zs0 = d01.x, zs1 = d01.y, zs2 = d23.x, zs3 = d23.y;
            float num = zs4 - zs0 * zs1 * inv_nw;
            float d0  = zs2 - zs0 * zs0 * inv_nw;
            float d1  = zs3 - zs1 * zs1 * inv_nw;
            float den = d0 * d1;
            if (den > 1e-5f) {
              float ncc = num * __frsqrt_rn(den);
              if (ncc >= LO && ncc <= HI) {
                float v = 0.5f * (d0 + d1);
                p_snv += ncc * v; p_sn += ncc; p_sv += v; p_cnt += 1.f;
                p_vmin = fminf(p_vmin, v);
              }
            }
          }
          H01[u] = P01; H23[u] = P23; H4[u] = P4;   // now holds P(s), read back at s+7
        }
        if (s + 1 < nslice) storeA();         // vmcnt wait lands HERE
        LDS_SYNC();
      }
    }
  }

  // ---- block reduce, global atomics, last-block finalize ----
  float bsnv = block_sum(p_snv, sm);
  float bsn  = block_sum(p_sn, sm);
  float bsv  = block_sum(p_sv, sm);
  float bcnt = block_sum(p_cnt, sm);
  float bmin = block_min(p_vmin, sm);
  if (tid == 0) {
    atomicAdd(&acc[0], bsnv);
    atomicAdd(&acc[1], bsn);
    atomicAdd(&acc[2], bsv);
    atomicAdd(&acc[3], bcnt);
    atomicMin((unsigned*)acc + 4, mono_f2u(bmin));
    __threadfence();
    unsigned prev = atomicAdd((unsigned*)acc + 5, 1u);
    if (prev == NB - 1) {
      float snv = atomicAdd(&acc[0], 0.f);
      float sn  = atomicAdd(&acc[1], 0.f);
      float sv  = atomicAdd(&acc[2], 0.f);
      float cnt = atomicAdd(&acc[3], 0.f);
      unsigned um = atomicMin((unsigned*)acc + 4, 0xFFFFFFFFu);
      unsigned bits = (um & 0x80000000u) ? (um ^ 0x80000000u) : ~um;
      float vmin = __uint_as_float(bits);
      // loss = 1 - (S_nv - vmin*S_n)/(S_v - vmin*cnt); min-max scale cancels.
      out[0] = 1.0f - (snv - vmin * sn) / (sv - vmin * cnt);
    }
  }
}

extern "C" void kernel_launch(void* const* d_in, const int* in_sizes, int n_in,
                              void* d_out, int out_size, void* d_ws, size_t ws_size,
                              hipStream_t stream) {
  const float* X = (const float*)d_in[0];  // y_pred
  const float* Y = (const float*)d_in[1];  // y_true
  // d_in[2]: ones kernel, constant, unused.

  float* acc = (float*)d_ws;
  // [0..3]=sums:0, [4]=vmin-mono:0xFFFFFFFF, [5]=counter:0
  hipMemsetAsync(acc, 0, 16, stream);
  hipMemsetAsync((char*)acc + 16, 0xFF, 4, stream);
  hipMemsetAsync((char*)acc + 20, 0, 4, stream);

  dim3 g(NWO, NHO, NN * ZCH);
  ncc_fused<<<g, 256, 0, stream>>>(X, Y, acc, (float*)d_out);
}

// Round 11
// 299.826 us; speedup vs baseline: 1.0319x; 1.0319x over previous
//
#include <hip/hip_runtime.h>
#include <math.h>

// Problem geometry (fixed by setup_inputs)
#define NN 2
#define DD 160
#define HH 192
#define WW 160
#define DO 154   // DD-6
#define HO 186   // HH-6
#define WO 154   // WW-6

#define NWO 3    // wo tiles of 64
#define NHO 47   // ho tiles of 4
#define ZCH 8    // z chunks
#define ZOC 20   // ceil(DO/ZCH)
#define NB (NWO * NHO * NN * ZCH)   // 2256 blocks

// LDS-only barrier: s_waitcnt lgkmcnt(0) (vmcnt left outstanding) + s_barrier.
// Global prefetch loads stay in flight across the barrier (CK block_sync_lds).
#define LDS_SYNC() do { __builtin_amdgcn_s_waitcnt(0xC07F); __builtin_amdgcn_s_barrier(); } while (0)

__device__ __forceinline__ unsigned mono_f2u(float f) {
  unsigned u = __float_as_uint(f);
  return (u & 0x80000000u) ? ~u : (u | 0x80000000u);
}

__device__ __forceinline__ float block_sum(float v, float* sm) {
  int tid = threadIdx.x;
  sm[tid] = v;
  __syncthreads();
#pragma unroll
  for (int off = 128; off > 0; off >>= 1) {
    if (tid < off) sm[tid] += sm[tid + off];
    __syncthreads();
  }
  float r = sm[0];
  __syncthreads();
  return r;
}

__device__ __forceinline__ float block_min(float v, float* sm) {
  int tid = threadIdx.x;
  sm[tid] = v;
  __syncthreads();
#pragma unroll
  for (int off = 128; off > 0; off >>= 1) {
    if (tid < off) sm[tid] = fminf(sm[tid], sm[tid + off]);
    __syncthreads();
  }
  float r = sm[0];
  __syncthreads();
  return r;
}

// acc layout (floats): [0..3] = snv, sn, sv, cnt (zeroed);
// [4] = vmin monotone-uint (init 0xFFFFFFFF); [5] = arrival counter (zeroed).
__global__ __launch_bounds__(256, 4) void ncc_fused(const float* __restrict__ X,
                                                    const float* __restrict__ Y,
                                                    float* __restrict__ acc,
                                                    float* __restrict__ out) {
  __shared__ __align__(16) float R[5][10][64];   // 12.8 KB W-filtered moment rows
  __shared__ __align__(16) float Mh[5][4][64];   // 5 KB   W+H-filtered moments
  __shared__ float sm[256];

  const int tid = threadIdx.x;
  const int tx = tid & 63, ty = tid >> 6;
  const int wo0 = blockIdx.x * 64;
  const int ho0 = blockIdx.y * 4;
  const int n   = blockIdx.z >> 3;   // ZCH == 8
  const int ck  = blockIdx.z & 7;
  const int z0  = ck * ZOC;
  const int zout = min(ZOC, DO - z0);
  const int nslice = zout + 6;

  const int wo = wo0 + tx, ho = ho0 + ty;
  const bool act = (wo < WO) && (ho < HO);

  const size_t slice = (size_t)HH * WW;
  const float* Xn = X + (size_t)n * DD * slice;
  const float* Yn = Y + (size_t)n * DD * slice;
  const float inv_nw = 1.0f / 343.0f;
  const float LO = -1.0f - 1e-5f, HI = 1.0f + 1e-5f;

  // Phase-A quad item: 160 items, item p -> row r=p>>4 (0..9), cols cq..cq+3.
  const int pA  = tid;
  const bool hasA = (pA < 160);
  const int rA  = pA >> 4;
  const int cqA = (pA & 15) << 2;
  const int hA  = ho0 + rA;
  const int baseW = wo0 + cqA;                 // multiple of 4, <=152 when valid
  const bool okA  = hasA && (hA < HH) && (baseW < WO);
  const bool tail = okA && (baseW + 9 >= WW);  // last float2 would cross the row
  const float* XrowA = Xn + (size_t)hA * WW + baseW;
  const float* YrowA = Yn + (size_t)hA * WW + baseW;

  float4 lx0 = {0,0,0,0}, lx1 = {0,0,0,0}, ly0 = {0,0,0,0}, ly1 = {0,0,0,0};
  float2 lx2 = {0,0}, ly2 = {0,0};

  auto loadA = [&](int s_in) {
    if (okA) {
      const float* xp = XrowA + (size_t)(z0 + s_in) * slice;
      const float* yp = YrowA + (size_t)(z0 + s_in) * slice;
      lx0 = *(const float4*)xp; lx1 = *(const float4*)(xp + 4);
      ly0 = *(const float4*)yp; ly1 = *(const float4*)(yp + 4);
      if (!tail) { lx2 = *(const float2*)(xp + 8); ly2 = *(const float2*)(yp + 8); }
      else       { lx2 = make_float2(0.f, 0.f);    ly2 = make_float2(0.f, 0.f); }
    }
  };

  auto storeA = [&]() {
    if (okA) {
      float x0=lx0.x,x1=lx0.y,x2=lx0.z,x3=lx0.w,x4=lx1.x,x5=lx1.y,x6=lx1.z,x7=lx1.w,x8=lx2.x,x9=lx2.y;
      float y0=ly0.x,y1=ly0.y,y2=ly0.z,y3=ly0.w,y4=ly1.x,y5=ly1.y,y6=ly1.z,y7=ly1.w,y8=ly2.x,y9=ly2.y;
      {
        float a = x0+x1+x2+x3+x4+x5+x6;
        float b = a - x0 + x7, c = b - x1 + x8, d = c - x2 + x9;
        *(float4*)&R[0][rA][cqA] = make_float4(a, b, c, d);
      }
      {
        float a = y0+y1+y2+y3+y4+y5+y6;
        float b = a - y0 + y7, c = b - y1 + y8, d = c - y2 + y9;
        *(float4*)&R[1][rA][cqA] = make_float4(a, b, c, d);
      }
      {
        float a = x0*x0+x1*x1+x2*x2+x3*x3+x4*x4+x5*x5+x6*x6;
        float b = a - x0*x0 + x7*x7, c = b - x1*x1 + x8*x8, d = c - x2*x2 + x9*x9;
        *(float4*)&R[2][rA][cqA] = make_float4(a, b, c, d);
      }
      {
        float a = y0*y0+y1*y1+y2*y2+y3*y3+y4*y4+y5*y5+y6*y6;
        float b = a - y0*y0 + y7*y7, c = b - y1*y1 + y8*y8, d = c - y2*y2 + y9*y9;
        *(float4*)&R[3][rA][cqA] = make_float4(a, b, c, d);
      }
      {
        float a = x0*y0+x1*y1+x2*y2+x3*y3+x4*y4+x5*y5+x6*y6;
        float b = a - x0*y0 + x7*y7, c = b - x1*y1 + x8*y8, d = c - x2*y2 + x9*y9;
        *(float4*)&R[4][rA][cqA] = make_float4(a, b, c, d);
      }
    }
  };

  // Phase H: incremental 7-tap H-sums (10 reads -> 4 outputs per (ch,wo)).
  // Items 0..255: ch=ty. Items 256..319 (ch=4) run on wave 3 at full density.
  auto phaseH = [&]() {
    {
      const int ch = ty, w = tx;
      const float* rp = &R[ch][0][w];
      float r0=rp[0],r1=rp[64],r2=rp[128],r3=rp[192],r4=rp[256],
            r5=rp[320],r6=rp[384],r7=rp[448],r8=rp[512],r9=rp[576];
      float m0 = r0+r1+r2+r3+r4+r5+r6;
      float m1 = m0 - r0 + r7, m2 = m1 - r1 + r8, m3 = m2 - r2 + r9;
      Mh[ch][0][w]=m0; Mh[ch][1][w]=m1; Mh[ch][2][w]=m2; Mh[ch][3][w]=m3;
    }
    if (tid >= 192) {
      const int w = tid - 192;
      const float* rp = &R[4][0][w];
      float r0=rp[0],r1=rp[64],r2=rp[128],r3=rp[192],r4=rp[256],
            r5=rp[320],r6=rp[384],r7=rp[448],r8=rp[512],r9=rp[576];
      float m0 = r0+r1+r2+r3+r4+r5+r6;
      float m1 = m0 - r0 + r7, m2 = m1 - r1 + r8, m3 = m2 - r2 + r9;
      Mh[4][0][w]=m0; Mh[4][1][w]=m1; Mh[4][2][w]=m2; Mh[4][3][w]=m3;
    }
  };

  // z-window via per-chunk prefix sums + 7-deep history (compile-time u index).
  // window(s) = P(s) - P(s-7);  H[u] holds P(s-7) when processing phase u.
  float P0 = 0.f, P1 = 0.f, P2 = 0.f, P3 = 0.f, P4 = 0.f;
  float H0[7], H1[7], H2[7], H3[7], H4[7];
#pragma unroll
  for (int j = 0; j < 7; ++j) { H0[j]=0.f; H1[j]=0.f; H2[j]=0.f; H3[j]=0.f; H4[j]=0.f; }
  float p_snv = 0.f, p_sn = 0.f, p_sv = 0.f, p_cnt = 0.f, p_vmin = 3.4e38f;

  loadA(0);
  storeA();
  __syncthreads();

  for (int sb = 0; sb < nslice; sb += 7) {
#pragma unroll
    for (int u = 0; u < 7; ++u) {
      const int s = sb + u;
      if (s < nslice) {                       // block-uniform
        if (s + 1 < nslice) loadA(s + 1);     // global -> regs (stays in flight)
        phaseH();                             // R -> Mh
        LDS_SYNC();
        {                                      // Phase O: prefix + window diff + NCC
          float m0 = Mh[0][ty][tx], m1 = Mh[1][ty][tx], m2 = Mh[2][ty][tx],
                m3 = Mh[3][ty][tx], m4 = Mh[4][ty][tx];
          P0 += m0; P1 += m1; P2 += m2; P3 += m3; P4 += m4;
          if (s >= 6 && act) {
            float zs0 = P0 - H0[u], zs1 = P1 - H1[u], zs2 = P2 - H2[u],
                  zs3 = P3 - H3[u], zs4 = P4 - H4[u];
            float num = zs4 - zs0 * zs1 * inv_nw;
            float d0  = zs2 - zs0 * zs0 * inv_nw;
            float d1  = zs3 - zs1 * zs1 * inv_nw;
            float den = d0 * d1;
            if (den > 1e-5f) {
              float ncc = num * __frsqrt_rn(den);
              if (ncc >= LO && ncc <= HI) {
                float v = 0.5f * (d0 + d1);
                p_snv += ncc * v; p_sn += ncc; p_sv += v; p_cnt += 1.f;
                p_vmin = fminf(p_vmin, v);
              }
            }
          }
          H0[u] = P0; H1[u] = P1; H2[u] = P2; H3[u] = P3; H4[u] = P4;
        }
        if (s + 1 < nslice) storeA();         // vmcnt wait lands HERE
        LDS_SYNC();
      }
    }
  }

  // ---- block reduce, global atomics, last-block finalize ----
  float bsnv = block_sum(p_snv, sm);
  float bsn  = block_sum(p_sn, sm);
  float bsv  = block_sum(p_sv, sm);
  float bcnt = block_sum(p_cnt, sm);
  float bmin = block_min(p_vmin, sm);
  if (tid == 0) {
    atomicAdd(&acc[0], bsnv);
    atomicAdd(&acc[1], bsn);
    atomicAdd(&acc[2], bsv);
    atomicAdd(&acc[3], bcnt);
    atomicMin((unsigned*)acc + 4, mono_f2u(bmin));
    __threadfence();
    unsigned prev = atomicAdd((unsigned*)acc + 5, 1u);
    if (prev == NB - 1) {
      // last block: read back via no-op RMW atomics (device-scope coherent)
      float snv = atomicAdd(&acc[0], 0.f);
      float sn  = atomicAdd(&acc[1], 0.f);
      float sv  = atomicAdd(&acc[2], 0.f);
      float cnt = atomicAdd(&acc[3], 0.f);
      unsigned um = atomicMin((unsigned*)acc + 4, 0xFFFFFFFFu);
      unsigned bits = (um & 0x80000000u) ? (um ^ 0x80000000u) : ~um;
      float vmin = __uint_as_float(bits);
      // loss = 1 - (S_nv - vmin*S_n)/(S_v - vmin*cnt); min-max scale cancels.
      out[0] = 1.0f - (snv - vmin * sn) / (sv - vmin * cnt);
    }
  }
}

extern "C" void kernel_launch(void* const* d_in, const int* in_sizes, int n_in,
                              void* d_out, int out_size, void* d_ws, size_t ws_size,
                              hipStream_t stream) {
  const float* X = (const float*)d_in[0];  // y_pred
  const float* Y = (const float*)d_in[1];  // y_true
  // d_in[2]: ones kernel, constant, unused.

  float* acc = (float*)d_ws;
  // [0..3]=sums:0, [4]=vmin-mono:0xFFFFFFFF, [5]=counter:0
  hipMemsetAsync(acc, 0, 16, stream);
  hipMemsetAsync((char*)acc + 16, 0xFF, 4, stream);
  hipMemsetAsync((char*)acc + 20, 0, 4, stream);

  dim3 g(NWO, NHO, NN * ZCH);
  ncc_fused<<<g, 256, 0, stream>>>(X, Y, acc, (float*)d_out);
}

// Round 12
// 177.285 us; speedup vs baseline: 1.7452x; 1.6912x over previous
//
#include <hip/hip_runtime.h>
#include <math.h>

// Problem geometry (fixed by setup_inputs)
#define NN 2
#define DD 160
#define HH 192
#define WW 160
#define DO 154   // DD-6
#define HO 186   // HH-6
#define WO 154   // WW-6

#define NWO 3    // wo tiles of 64
#define NHO 47   // ho tiles of 4
#define ZCH 8    // z chunks
#define ZOC 20   // ceil(DO/ZCH)
#define NB (NWO * NHO * NN * ZCH)   // 2256 blocks

// LDS-only barrier: s_waitcnt lgkmcnt(0) (vmcnt left outstanding) + s_barrier.
// Global prefetch loads stay in flight across the barrier (CK block_sync_lds).
#define LDS_SYNC() do { __builtin_amdgcn_s_waitcnt(0xC07F); __builtin_amdgcn_s_barrier(); } while (0)

__device__ __forceinline__ float block_sum(float v, float* sm) {
  int tid = threadIdx.x;
  sm[tid] = v;
  __syncthreads();
#pragma unroll
  for (int off = 128; off > 0; off >>= 1) {
    if (tid < off) sm[tid] += sm[tid + off];
    __syncthreads();
  }
  float r = sm[0];
  __syncthreads();
  return r;
}

__device__ __forceinline__ float block_min(float v, float* sm) {
  int tid = threadIdx.x;
  sm[tid] = v;
  __syncthreads();
#pragma unroll
  for (int off = 128; off > 0; off >>= 1) {
    if (tid < off) sm[tid] = fminf(sm[tid], sm[tid + off]);
    __syncthreads();
  }
  float r = sm[0];
  __syncthreads();
  return r;
}

__global__ __launch_bounds__(256, 4) void ncc_fused(const float* __restrict__ X,
                                                    const float* __restrict__ Y,
                                                    float* __restrict__ part) {
  __shared__ __align__(16) float R[5][10][64];   // 12.8 KB W-filtered moment rows
  __shared__ __align__(16) float Mh[5][4][64];   // 5 KB   W+H-filtered moments
  __shared__ float sm[256];

  const int tid = threadIdx.x;
  const int tx = tid & 63, ty = tid >> 6;
  const int wo0 = blockIdx.x * 64;
  const int ho0 = blockIdx.y * 4;
  const int n   = blockIdx.z >> 3;   // ZCH == 8
  const int ck  = blockIdx.z & 7;
  const int z0  = ck * ZOC;
  const int zout = min(ZOC, DO - z0);
  const int nslice = zout + 6;

  const int wo = wo0 + tx, ho = ho0 + ty;
  const bool act = (wo < WO) && (ho < HO);

  const size_t slice = (size_t)HH * WW;
  const float* Xn = X + (size_t)n * DD * slice;
  const float* Yn = Y + (size_t)n * DD * slice;
  const float inv_nw = 1.0f / 343.0f;
  const float LO = -1.0f - 1e-5f, HI = 1.0f + 1e-5f;

  // Phase-A quad item: 160 items, item p -> row r=p>>4 (0..9), cols cq..cq+3.
  const int pA  = tid;
  const bool hasA = (pA < 160);
  const int rA  = pA >> 4;
  const int cqA = (pA & 15) << 2;
  const int hA  = ho0 + rA;
  const int baseW = wo0 + cqA;                 // multiple of 4, <=152 when valid
  const bool okA  = hasA && (hA < HH) && (baseW < WO);
  const bool tail = okA && (baseW + 9 >= WW);  // last float2 would cross the row
  const float* XrowA = Xn + (size_t)hA * WW + baseW;
  const float* YrowA = Yn + (size_t)hA * WW + baseW;

  float4 lx0 = {0,0,0,0}, lx1 = {0,0,0,0}, ly0 = {0,0,0,0}, ly1 = {0,0,0,0};
  float2 lx2 = {0,0}, ly2 = {0,0};

  auto loadA = [&](int s_in) {
    if (okA) {
      const float* xp = XrowA + (size_t)(z0 + s_in) * slice;
      const float* yp = YrowA + (size_t)(z0 + s_in) * slice;
      lx0 = *(const float4*)xp; lx1 = *(const float4*)(xp + 4);
      ly0 = *(const float4*)yp; ly1 = *(const float4*)(yp + 4);
      if (!tail) { lx2 = *(const float2*)(xp + 8); ly2 = *(const float2*)(yp + 8); }
      else       { lx2 = make_float2(0.f, 0.f);    ly2 = make_float2(0.f, 0.f); }
    }
  };

  auto storeA = [&]() {
    if (okA) {
      float x0=lx0.x,x1=lx0.y,x2=lx0.z,x3=lx0.w,x4=lx1.x,x5=lx1.y,x6=lx1.z,x7=lx1.w,x8=lx2.x,x9=lx2.y;
      float y0=ly0.x,y1=ly0.y,y2=ly0.z,y3=ly0.w,y4=ly1.x,y5=ly1.y,y6=ly1.z,y7=ly1.w,y8=ly2.x,y9=ly2.y;
      {
        float a = x0+x1+x2+x3+x4+x5+x6;
        float b = a - x0 + x7, c = b - x1 + x8, d = c - x2 + x9;
        *(float4*)&R[0][rA][cqA] = make_float4(a, b, c, d);
      }
      {
        float a = y0+y1+y2+y3+y4+y5+y6;
        float b = a - y0 + y7, c = b - y1 + y8, d = c - y2 + y9;
        *(float4*)&R[1][rA][cqA] = make_float4(a, b, c, d);
      }
      {
        float a = x0*x0+x1*x1+x2*x2+x3*x3+x4*x4+x5*x5+x6*x6;
        float b = a - x0*x0 + x7*x7, c = b - x1*x1 + x8*x8, d = c - x2*x2 + x9*x9;
        *(float4*)&R[2][rA][cqA] = make_float4(a, b, c, d);
      }
      {
        float a = y0*y0+y1*y1+y2*y2+y3*y3+y4*y4+y5*y5+y6*y6;
        float b = a - y0*y0 + y7*y7, c = b - y1*y1 + y8*y8, d = c - y2*y2 + y9*y9;
        *(float4*)&R[3][rA][cqA] = make_float4(a, b, c, d);
      }
      {
        float a = x0*y0+x1*y1+x2*y2+x3*y3+x4*y4+x5*y5+x6*y6;
        float b = a - x0*y0 + x7*y7, c = b - x1*y1 + x8*y8, d = c - x2*y2 + x9*y9;
        *(float4*)&R[4][rA][cqA] = make_float4(a, b, c, d);
      }
    }
  };

  // Phase H: incremental 7-tap H-sums (10 reads -> 4 outputs per (ch,wo)).
  // Items 0..255: ch=ty. Items 256..319 (ch=4): 16 lanes in each wave.
  auto phaseH = [&]() {
    {
      const int ch = ty, w = tx;
      const float* rp = &R[ch][0][w];
      float r0=rp[0],r1=rp[64],r2=rp[128],r3=rp[192],r4=rp[256],
            r5=rp[320],r6=rp[384],r7=rp[448],r8=rp[512],r9=rp[576];
      float m0 = r0+r1+r2+r3+r4+r5+r6;
      float m1 = m0 - r0 + r7, m2 = m1 - r1 + r8, m3 = m2 - r2 + r9;
      Mh[ch][0][w]=m0; Mh[ch][1][w]=m1; Mh[ch][2][w]=m2; Mh[ch][3][w]=m3;
    }
    if (tx < 16) {
      const int w = ty * 16 + tx;
      const float* rp = &R[4][0][w];
      float r0=rp[0],r1=rp[64],r2=rp[128],r3=rp[192],r4=rp[256],
            r5=rp[320],r6=rp[384],r7=rp[448],r8=rp[512],r9=rp[576];
      float m0 = r0+r1+r2+r3+r4+r5+r6;
      float m1 = m0 - r0 + r7, m2 = m1 - r1 + r8, m3 = m2 - r2 + r9;
      Mh[4][0][w]=m0; Mh[4][1][w]=m1; Mh[4][2][w]=m2; Mh[4][3][w]=m3;
    }
  };

  // Rotating 7-phase accumulators (no ring storage, no shift movs).
  float a0[7], a1[7], a2[7], a3[7], a4[7];
#pragma unroll
  for (int j = 0; j < 7; ++j) { a0[j]=0.f; a1[j]=0.f; a2[j]=0.f; a3[j]=0.f; a4[j]=0.f; }
  float p_snv = 0.f, p_sn = 0.f, p_sv = 0.f, p_cnt = 0.f, p_vmin = 3.4e38f;

  loadA(0);
  storeA();
  __syncthreads();

  for (int sb = 0; sb < nslice; sb += 7) {
#pragma unroll
    for (int u = 0; u < 7; ++u) {
      const int s = sb + u;
      if (s < nslice) {                       // wave-uniform
        if (s + 1 < nslice) loadA(s + 1);     // global -> regs (stays in flight)
        phaseH();                             // R -> Mh
        LDS_SYNC();
        {                                      // Phase O: Mh -> accumulators
          float m0 = Mh[0][ty][tx], m1 = Mh[1][ty][tx], m2 = Mh[2][ty][tx],
                m3 = Mh[3][ty][tx], m4 = Mh[4][ty][tx];
#pragma unroll
          for (int j = 0; j < 7; ++j) {
            a0[j]+=m0; a1[j]+=m1; a2[j]+=m2; a3[j]+=m3; a4[j]+=m4;
          }
          if (s >= 6 && act) {
            float zs0=a0[u], zs1=a1[u], zs2=a2[u], zs3=a3[u], zs4=a4[u];
            float num = zs4 - zs0 * zs1 * inv_nw;
            float d0  = zs2 - zs0 * zs0 * inv_nw;
            float d1  = zs3 - zs1 * zs1 * inv_nw;
            float den = d0 * d1;
            if (den > 1e-5f) {
              float ncc = num * __frsqrt_rn(den);
              if (ncc >= LO && ncc <= HI) {
                float v = 0.5f * (d0 + d1);
                p_snv += ncc * v; p_sn += ncc; p_sv += v; p_cnt += 1.f;
                p_vmin = fminf(p_vmin, v);
              }
            }
          }
          a0[u]=0.f; a1[u]=0.f; a2[u]=0.f; a3[u]=0.f; a4[u]=0.f;
        }
        if (s + 1 < nslice) storeA();         // vmcnt wait lands HERE
        LDS_SYNC();
      }
    }
  }

  float bsnv = block_sum(p_snv, sm);
  float bsn  = block_sum(p_sn, sm);
  float bsv  = block_sum(p_sv, sm);
  float bcnt = block_sum(p_cnt, sm);
  float bmin = block_min(p_vmin, sm);
  if (tid == 0) {
    const int bid = blockIdx.x + NWO * (blockIdx.y + NHO * blockIdx.z);
    float* pp = part + (size_t)bid * 8;
    pp[0] = bsnv; pp[1] = bsn; pp[2] = bsv; pp[3] = bcnt; pp[4] = bmin;
  }
}

// Reduce NB per-block partials; loss = 1 - (S_nv - vmin*S_n)/(S_v - vmin*cnt)
// (the min-max weight scale HIGH/(vmax-vmin+1e-12) cancels in w/sum(w)).
__global__ __launch_bounds__(256) void fin(const float* __restrict__ part,
                                           float* __restrict__ out) {
  __shared__ float sm[256];
  const int tid = threadIdx.x;
  float s0 = 0.f, s1 = 0.f, s2 = 0.f, s3 = 0.f, vm = 3.4e38f;
  for (int b = tid; b < NB; b += 256) {
    const float* pp = part + (size_t)b * 8;
    s0 += pp[0]; s1 += pp[1]; s2 += pp[2]; s3 += pp[3];
    vm = fminf(vm, pp[4]);
  }
  s0 = block_sum(s0, sm);
  s1 = block_sum(s1, sm);
  s2 = block_sum(s2, sm);
  s3 = block_sum(s3, sm);
  vm = block_min(vm, sm);
  if (tid == 0) {
    out[0] = 1.0f - (s0 - vm * s1) / (s2 - vm * s3);
  }
}

extern "C" void kernel_launch(void* const* d_in, const int* in_sizes, int n_in,
                              void* d_out, int out_size, void* d_ws, size_t ws_size,
                              hipStream_t stream) {
  const float* X = (const float*)d_in[0];  // y_pred
  const float* Y = (const float*)d_in[1];  // y_true
  // d_in[2]: ones kernel, constant, unused.

  float* part = (float*)d_ws;  // NB * 8 floats = 72 KB

  dim3 g(NWO, NHO, NN * ZCH);
  ncc_fused<<<g, 256, 0, stream>>>(X, Y, part);
  fin<<<1, 256, 0, stream>>>(part, (float*)d_out);
}